// Round 2
// baseline (44.376 us; speedup 1.0000x reference)
//
#include <hip/hip_runtime.h>

typedef __attribute__((ext_vector_type(8))) short bf16x8;
typedef __attribute__((ext_vector_type(4))) float f32x4;

// round-to-nearest-even fp32 -> bf16 (bit pattern in a short)
__device__ __forceinline__ short f2bs(float f) {
    unsigned int u = __float_as_uint(f);
    unsigned int r = (u + 0x7fffu + ((u >> 16) & 1u)) >> 16;
    return (short)r;
}

// ---------------------------------------------------------------------------
// prep kernel: pack Wc = [W1 | ref^T] (256 x 96) and W2 (32 x 16) into bf16
// MFMA B-fragment order, compute r2[j] = ||ref_j||^2.
//   wcfrag layout: [kt(8)][nt(6)][lane(64)][j(8)]  (ushort)
//     k = kt*32 + (lane>>4)*8 + j ; col = nt*16 + (lane&15)
//   w2frag layout: [lane(64)][j(8)]  k=(lane>>4)*8+j, col=lane&15
// ---------------------------------------------------------------------------
__global__ void prep_kernel(const float* __restrict__ W1,
                            const float* __restrict__ ref,
                            const float* __restrict__ W2,
                            float* __restrict__ r2,
                            unsigned short* __restrict__ wcfrag,
                            unsigned short* __restrict__ w2frag) {
    int idx = blockIdx.x * 256 + threadIdx.x;
    if (idx < 24576) {
        int j    = idx & 7;
        int lane = (idx >> 3) & 63;
        int nt   = (idx >> 9) % 6;
        int kt   = idx / 3072;
        int k    = kt * 32 + (lane >> 4) * 8 + j;
        int col  = nt * 16 + (lane & 15);
        float w  = (col < 32) ? W1[k * 32 + col] : ref[(col - 32) * 256 + k];
        wcfrag[idx] = (unsigned short)f2bs(w);
    } else if (idx < 24576 + 512) {
        int t    = idx - 24576;
        int j    = t & 7;
        int lane = t >> 3;
        int k    = (lane >> 4) * 8 + j;
        int col  = lane & 15;
        w2frag[t] = (unsigned short)f2bs(W2[k * 16 + col]);
    } else if (idx < 24576 + 512 + 64) {
        int t = idx - (24576 + 512);
        float s = 0.f;
        for (int k = 0; k < 256; ++k) {
            float v = ref[t * 256 + k];
            s += v * v;
        }
        r2[t] = s;
    }
}

// ---------------------------------------------------------------------------
// main fused kernel: 256 threads (4 waves), 128 rows per block.
// Y = x @ [W1|ref^T] via mfma 16x16x32 bf16; fused epilogue:
//   h1 = relu(Y[:, :32]+b1) ; h2 = relu(h1@W2+b2) (2nd MFMA)
//   kf = exp(-(x2 + r2 - 2*Y[:,32:])) ; out = h2@Wf[:16] + kf@Wf[16:] + bf
// B-fragments read directly from global (L1/L2-resident, coalesced 1KB/inst).
// All LDS is wave-private (h1 transpose + x2 exchange) -> ZERO barriers.
// ---------------------------------------------------------------------------
__global__ __launch_bounds__(256, 4) void fused_kernel(
        const float* __restrict__ x,
        const float* __restrict__ b1,
        const float* __restrict__ b2,
        const float* __restrict__ Wf,
        const float* __restrict__ bfp,
        const float* __restrict__ r2g,
        const unsigned short* __restrict__ wcfrag,
        const unsigned short* __restrict__ w2frag,
        float* __restrict__ out) {
    __shared__ unsigned short h1lds[128][40];    // 10 KB (80B row stride)
    __shared__ float x2s[128];                   // 0.5 KB

    const int tid  = threadIdx.x;
    const int lane = tid & 63;
    const int w    = tid >> 6;

    // ---- K loop: Y = x @ Wc ----
    const int rowblk = w * 32;                        // wave's row base within block
    const long long r0 = (long long)blockIdx.x * 128 + rowblk + (lane & 15);
    const float* xp0 = x + r0 * 256 + ((lane >> 4) * 8);
    const float* xp1 = xp0 + 16 * 256;
    const bf16x8* wcp = (const bf16x8*)(wcfrag + lane * 8);   // + (kt*6+nt)*512

    f32x4 acc[2][6];
    #pragma unroll
    for (int fr = 0; fr < 2; ++fr)
        #pragma unroll
        for (int nt = 0; nt < 6; ++nt)
            acc[fr][nt] = (f32x4){0.f, 0.f, 0.f, 0.f};

    float x2p0 = 0.f, x2p1 = 0.f;

    #pragma unroll 2
    for (int kt = 0; kt < 8; ++kt) {
        const f32x4* p0 = (const f32x4*)(xp0 + kt * 32);
        const f32x4* p1 = (const f32x4*)(xp1 + kt * 32);
        f32x4 u0 = __builtin_nontemporal_load(p0);
        f32x4 u1 = __builtin_nontemporal_load(p0 + 1);
        f32x4 v0 = __builtin_nontemporal_load(p1);
        f32x4 v1 = __builtin_nontemporal_load(p1 + 1);

        bf16x8 a0, a1;
        #pragma unroll
        for (int j = 0; j < 4; ++j) {
            a0[j]     = f2bs(u0[j]);
            a0[j + 4] = f2bs(u1[j]);
            a1[j]     = f2bs(v0[j]);
            a1[j + 4] = f2bs(v1[j]);
            x2p0 += u0[j] * u0[j] + u1[j] * u1[j];
            x2p1 += v0[j] * v0[j] + v1[j] * v1[j];
        }

        #pragma unroll
        for (int nt = 0; nt < 6; ++nt) {
            bf16x8 bfr = wcp[(kt * 6 + nt) * 64];
            acc[0][nt] = __builtin_amdgcn_mfma_f32_16x16x32_bf16(a0, bfr, acc[0][nt], 0, 0, 0);
            acc[1][nt] = __builtin_amdgcn_mfma_f32_16x16x32_bf16(a1, bfr, acc[1][nt], 0, 0, 0);
        }
    }

    // ---- x2: reduce over the 4 k-groups (lanes xor 16, 32) ----
    x2p0 += __shfl_xor(x2p0, 16);
    x2p0 += __shfl_xor(x2p0, 32);
    x2p1 += __shfl_xor(x2p1, 16);
    x2p1 += __shfl_xor(x2p1, 32);
    if (lane < 16) {
        x2s[rowblk + lane]      = x2p0;
        x2s[rowblk + 16 + lane] = x2p1;
    }

    // ---- h1 = relu(Y[:, :32] + b1) -> LDS (bf16, transposed for 2nd MFMA) ----
    const int colm = lane & 15;
    const float b1a = b1[colm];
    const float b1b = b1[16 + colm];
    #pragma unroll
    for (int fr = 0; fr < 2; ++fr)
        #pragma unroll
        for (int nt = 0; nt < 2; ++nt)
            #pragma unroll
            for (int r = 0; r < 4; ++r) {
                int row = rowblk + fr * 16 + (lane >> 4) * 4 + r;
                int col = nt * 16 + colm;
                float hv = fmaxf(acc[fr][nt][r] + (nt == 0 ? b1a : b1b), 0.f);
                h1lds[row][col] = (unsigned short)f2bs(hv);
            }
    // same-wave LDS RAW only (each wave owns its 32 rows): no barrier needed.

    // ---- h2 = relu(h1 @ W2 + b2) via MFMA ----
    bf16x8 w2f = *(const bf16x8*)(w2frag + lane * 8);
    f32x4 hacc[2];
    #pragma unroll
    for (int fr = 0; fr < 2; ++fr) {
        int row = rowblk + fr * 16 + (lane & 15);
        bf16x8 af = *(const bf16x8*)&h1lds[row][(lane >> 4) * 8];
        f32x4 z = (f32x4){0.f, 0.f, 0.f, 0.f};
        hacc[fr] = __builtin_amdgcn_mfma_f32_16x16x32_bf16(af, w2f, z, 0, 0, 0);
    }

    // ---- combine: out = h2@Wf[:16] + kf@Wf[16:] + bf ----
    const float wfm = Wf[colm];
    const float b2v = b2[colm];
    const float bfv = bfp[0];
    float r2v[4], wfv[4];
    #pragma unroll
    for (int nt = 0; nt < 4; ++nt) {
        int jj = nt * 16 + colm;
        r2v[nt] = r2g[jj];
        wfv[nt] = Wf[16 + jj];
    }
    #pragma unroll
    for (int fr = 0; fr < 2; ++fr) {
        float osum[4];
        #pragma unroll
        for (int r = 0; r < 4; ++r) {
            int row = rowblk + fr * 16 + (lane >> 4) * 4 + r;
            float h2v = fmaxf(hacc[fr][r] + b2v, 0.f);
            float s = h2v * wfm;
            float x2v = x2s[row];
            #pragma unroll
            for (int nt = 0; nt < 4; ++nt) {
                float sq = x2v + r2v[nt] - 2.f * acc[fr][nt + 2][r];
                s += __expf(-sq) * wfv[nt];
            }
            // butterfly sum over the 16 lanes sharing this row
            s += __shfl_xor(s, 1);
            s += __shfl_xor(s, 2);
            s += __shfl_xor(s, 4);
            s += __shfl_xor(s, 8);
            osum[r] = s + bfv;
        }
        if (colm == 0) {
            long long rowg = (long long)blockIdx.x * 128 + rowblk + fr * 16 + (lane >> 4) * 4;
            #pragma unroll
            for (int r = 0; r < 4; ++r) out[rowg + r] = osum[r];
        }
    }
}

extern "C" void kernel_launch(void* const* d_in, const int* in_sizes, int n_in,
                              void* d_out, int out_size, void* d_ws, size_t ws_size,
                              hipStream_t stream) {
    const float* x   = (const float*)d_in[0];
    const float* W1  = (const float*)d_in[1];
    const float* b1  = (const float*)d_in[2];
    const float* W2  = (const float*)d_in[3];
    const float* b2  = (const float*)d_in[4];
    const float* ref = (const float*)d_in[5];
    const float* Wf  = (const float*)d_in[6];
    const float* bf_ = (const float*)d_in[7];
    float* out = (float*)d_out;

    const int B = in_sizes[0] / 256;

    unsigned short* wcfrag = (unsigned short*)d_ws;                      // 49152 B
    unsigned short* w2frag = (unsigned short*)((char*)d_ws + 49152);     // 1024 B
    float*          r2     = (float*)((char*)d_ws + 49152 + 1024);       // 256 B

    hipLaunchKernelGGL(prep_kernel, dim3(99), dim3(256), 0, stream,
                       W1, ref, W2, r2, wcfrag, w2frag);
    hipLaunchKernelGGL(fused_kernel, dim3(B / 128), dim3(256), 0, stream,
                       x, b1, b2, Wf, bf_, r2, wcfrag, w2frag, out);
}

// Round 3
// 35.740 us; speedup vs baseline: 1.2416x; 1.2416x over previous
//
#include <hip/hip_runtime.h>

typedef __attribute__((ext_vector_type(8))) short bf16x8;
typedef __attribute__((ext_vector_type(4))) float f32x4;

// round-to-nearest-even fp32 -> bf16 (bit pattern in a short)
__device__ __forceinline__ short f2bs(float f) {
    unsigned int u = __float_as_uint(f);
    unsigned int r = (u + 0x7fffu + ((u >> 16) & 1u)) >> 16;
    return (short)r;
}

// ---------------------------------------------------------------------------
// prep kernel: pack Wc = [W1 | ref^T] (256 x 96) and W2 (32 x 16) into bf16
// MFMA B-fragment order, compute r2[j] = ||ref_j||^2.
//   wcfrag layout: [kt(8)][nt(6)][lane(64)][j(8)]  (ushort)
//     k = kt*32 + (lane>>4)*8 + j ; col = nt*16 + (lane&15)
//   w2frag layout: [lane(64)][j(8)]  k=(lane>>4)*8+j, col=lane&15
// ---------------------------------------------------------------------------
__global__ void prep_kernel(const float* __restrict__ W1,
                            const float* __restrict__ ref,
                            const float* __restrict__ W2,
                            float* __restrict__ r2,
                            unsigned short* __restrict__ wcfrag,
                            unsigned short* __restrict__ w2frag) {
    int idx = blockIdx.x * 256 + threadIdx.x;
    if (idx < 24576) {
        int j    = idx & 7;
        int lane = (idx >> 3) & 63;
        int nt   = (idx >> 9) % 6;
        int kt   = idx / 3072;
        int k    = kt * 32 + (lane >> 4) * 8 + j;
        int col  = nt * 16 + (lane & 15);
        float w  = (col < 32) ? W1[k * 32 + col] : ref[(col - 32) * 256 + k];
        wcfrag[idx] = (unsigned short)f2bs(w);
    } else if (idx < 24576 + 512) {
        int t    = idx - 24576;
        int j    = t & 7;
        int lane = t >> 3;
        int k    = (lane >> 4) * 8 + j;
        int col  = lane & 15;
        w2frag[t] = (unsigned short)f2bs(W2[k * 16 + col]);
    } else if (idx < 24576 + 512 + 64) {
        int t = idx - (24576 + 512);
        float s = 0.f;
        for (int k = 0; k < 256; ++k) {
            float v = ref[t * 256 + k];
            s += v * v;
        }
        r2[t] = s;
    }
}

// ---------------------------------------------------------------------------
// main fused kernel: 512 threads (8 waves), 128 rows per block, 16 rows/wave.
// Y = x @ [W1|ref^T] via mfma 16x16x32 bf16 (B from LDS); fused epilogue:
//   h1 = relu(Y[:, :32]+b1) ; h2 = relu(h1@W2+b2) (2nd MFMA)
//   kf = exp(-(x2 + r2 - 2*Y[:,32:])) ; out = h2@Wf[:16] + kf@Wf[16:] + bf
// One barrier total (after weight staging). All other LDS is wave-private.
// 16 rows/wave keeps acc at 24 VGPRs -> launch_bounds(512,4) = 4 waves/SIMD.
// ---------------------------------------------------------------------------
__global__ __launch_bounds__(512, 4) void fused_kernel(
        const float* __restrict__ x,
        const float* __restrict__ b1,
        const float* __restrict__ b2,
        const float* __restrict__ Wf,
        const float* __restrict__ bfp,
        const float* __restrict__ r2g,
        const unsigned short* __restrict__ wcfrag,
        const unsigned short* __restrict__ w2frag,
        float* __restrict__ out) {
    __shared__ unsigned short wc[8][6][64][8];   // 48 KB, fragment order
    __shared__ unsigned short h1lds[128][40];    // 10 KB (80B row stride)
    __shared__ float x2s[128];                   // 0.5 KB

    const int tid  = threadIdx.x;
    const int lane = tid & 63;
    const int w    = tid >> 6;

    // ---- prologue: stage weights (48 KB, 3072 int4 / 512 threads = 6 each) ----
    {
        const int4* src = (const int4*)wcfrag;
        int4* dst = (int4*)&wc[0][0][0][0];
        #pragma unroll
        for (int i = 0; i < 6; ++i) dst[tid + i * 512] = src[tid + i * 512];
    }
    __syncthreads();

    // ---- K loop: Y[16 rows] = x @ Wc ----
    const int rowblk = w * 16;                        // wave's row base within block
    const long long r0 = (long long)blockIdx.x * 128 + rowblk + (lane & 15);
    const float* xp0 = x + r0 * 256 + ((lane >> 4) * 8);

    f32x4 acc[6];
    #pragma unroll
    for (int nt = 0; nt < 6; ++nt)
        acc[nt] = (f32x4){0.f, 0.f, 0.f, 0.f};

    float x2p = 0.f;

    #pragma unroll 2
    for (int kt = 0; kt < 8; ++kt) {
        const f32x4* p0 = (const f32x4*)(xp0 + kt * 32);
        f32x4 u0 = p0[0], u1 = p0[1];

        bf16x8 a0;
        #pragma unroll
        for (int j = 0; j < 4; ++j) {
            a0[j]     = f2bs(u0[j]);
            a0[j + 4] = f2bs(u1[j]);
            x2p += u0[j] * u0[j] + u1[j] * u1[j];
        }

        #pragma unroll
        for (int nt = 0; nt < 6; ++nt) {
            bf16x8 bfr = *(const bf16x8*)&wc[kt][nt][lane][0];
            acc[nt] = __builtin_amdgcn_mfma_f32_16x16x32_bf16(a0, bfr, acc[nt], 0, 0, 0);
        }
    }

    // ---- x2: reduce over the 4 k-groups (lanes xor 16, 32) ----
    x2p += __shfl_xor(x2p, 16);
    x2p += __shfl_xor(x2p, 32);
    if (lane < 16) x2s[rowblk + lane] = x2p;

    // ---- h1 = relu(Y[:, :32] + b1) -> LDS (bf16, transposed for 2nd MFMA) ----
    const int colm = lane & 15;
    const float b1a = b1[colm];
    const float b1b = b1[16 + colm];
    #pragma unroll
    for (int nt = 0; nt < 2; ++nt)
        #pragma unroll
        for (int r = 0; r < 4; ++r) {
            int row = rowblk + (lane >> 4) * 4 + r;
            int col = nt * 16 + colm;
            float hv = fmaxf(acc[nt][r] + (nt == 0 ? b1a : b1b), 0.f);
            h1lds[row][col] = (unsigned short)f2bs(hv);
        }
    // same-wave LDS RAW only (each wave owns its 16 rows): no barrier needed.

    // ---- h2 = relu(h1 @ W2 + b2) via MFMA ----
    bf16x8 w2f = *(const bf16x8*)(w2frag + lane * 8);
    bf16x8 af = *(const bf16x8*)&h1lds[rowblk + colm][(lane >> 4) * 8];
    f32x4 z = (f32x4){0.f, 0.f, 0.f, 0.f};
    f32x4 hacc = __builtin_amdgcn_mfma_f32_16x16x32_bf16(af, w2f, z, 0, 0, 0);

    // ---- combine: out = h2@Wf[:16] + kf@Wf[16:] + bf ----
    const float wfm = Wf[colm];
    const float b2v = b2[colm];
    const float bfv = bfp[0];
    float r2v[4], wfv[4];
    #pragma unroll
    for (int nt = 0; nt < 4; ++nt) {
        int jj = nt * 16 + colm;
        r2v[nt] = r2g[jj];
        wfv[nt] = Wf[16 + jj];
    }
    float osum[4];
    #pragma unroll
    for (int r = 0; r < 4; ++r) {
        int row = rowblk + (lane >> 4) * 4 + r;
        float h2v = fmaxf(hacc[r] + b2v, 0.f);
        float s = h2v * wfm;
        float x2v = x2s[row];
        #pragma unroll
        for (int nt = 0; nt < 4; ++nt) {
            float sq = x2v + r2v[nt] - 2.f * acc[nt + 2][r];
            s += __expf(-sq) * wfv[nt];
        }
        // butterfly sum over the 16 lanes sharing this row
        s += __shfl_xor(s, 1);
        s += __shfl_xor(s, 2);
        s += __shfl_xor(s, 4);
        s += __shfl_xor(s, 8);
        osum[r] = s + bfv;
    }
    if (colm == 0) {
        long long rowg = (long long)blockIdx.x * 128 + rowblk + (lane >> 4) * 4;
        #pragma unroll
        for (int r = 0; r < 4; ++r) out[rowg + r] = osum[r];
    }
}

extern "C" void kernel_launch(void* const* d_in, const int* in_sizes, int n_in,
                              void* d_out, int out_size, void* d_ws, size_t ws_size,
                              hipStream_t stream) {
    const float* x   = (const float*)d_in[0];
    const float* W1  = (const float*)d_in[1];
    const float* b1  = (const float*)d_in[2];
    const float* W2  = (const float*)d_in[3];
    const float* b2  = (const float*)d_in[4];
    const float* ref = (const float*)d_in[5];
    const float* Wf  = (const float*)d_in[6];
    const float* bf_ = (const float*)d_in[7];
    float* out = (float*)d_out;

    const int B = in_sizes[0] / 256;

    unsigned short* wcfrag = (unsigned short*)d_ws;                      // 49152 B
    unsigned short* w2frag = (unsigned short*)((char*)d_ws + 49152);     // 1024 B
    float*          r2     = (float*)((char*)d_ws + 49152 + 1024);       // 256 B

    hipLaunchKernelGGL(prep_kernel, dim3(99), dim3(256), 0, stream,
                       W1, ref, W2, r2, wcfrag, w2frag);
    hipLaunchKernelGGL(fused_kernel, dim3(B / 128), dim3(512), 0, stream,
                       x, b1, b2, Wf, bf_, r2, wcfrag, w2frag, out);
}